// Round 11
// baseline (227.607 us; speedup 1.0000x reference)
//
#include <hip/hip_runtime.h>
#include <hip/hip_bf16.h>
#include <math.h>

#define D 128
#define EPS 1e-12f

typedef __attribute__((ext_vector_type(8))) short bf16x8;
typedef __attribute__((ext_vector_type(4))) float f32x4;
typedef __attribute__((ext_vector_type(2))) float f32x2;

// float -> bf16 round-to-nearest-even (finite inputs)
__device__ __forceinline__ unsigned short f2bf(float f) {
    unsigned int u = __float_as_uint(f);
    return (unsigned short)((u + 0x7fffu + ((u >> 16) & 1u)) >> 16);
}
__device__ __forceinline__ float bf2f_lo(unsigned int packed) {
    return __uint_as_float(packed << 16);
}
__device__ __forceinline__ float bf2f_hi(unsigned int packed) {
    return __uint_as_float(packed & 0xffff0000u);
}
__device__ __forceinline__ unsigned char f2fp8(float f) {
    return (unsigned char)__builtin_amdgcn_cvt_pk_fp8_f32(f, f, 0, false);
}

// ---------------- W convert to MFMA-fragment order ----------------
// Fragment order: WT[m*16384 + ((ct*4+ks)*64 + quad*16 + l15)*8 + j]
//   holds element (n = ct*16+l15, k = ks*32+quad*8+j) of W_m^T  (bf16)
__global__ __launch_bounds__(256) void wconv_kernel(
    const float* __restrict__ Wq, const float* __restrict__ Wk,
    const float* __restrict__ Wv, const float* __restrict__ Wo,
    unsigned short* __restrict__ WT) {
    __shared__ unsigned short tile[32][33];
    int bx = blockIdx.x;
    int tid = threadIdx.x;
    int m = bx >> 4;
    int t = bx & 15;
    const float* W = (m == 0) ? Wq : (m == 1) ? Wk : (m == 2) ? Wv : Wo;
    int r0 = (t & 3) * 32;   // k block
    int c0 = (t >> 2) * 32;  // n block
    int row = tid >> 3, c4 = (tid & 7) * 4;
    float4 v = *(const float4*)&W[(size_t)(r0 + row) * D + c0 + c4];
    tile[c4 + 0][row] = f2bf(v.x);
    tile[c4 + 1][row] = f2bf(v.y);
    tile[c4 + 2][row] = f2bf(v.z);
    tile[c4 + 3][row] = f2bf(v.w);
    __syncthreads();
    unsigned int lo = (unsigned int)tile[row][c4] | ((unsigned int)tile[row][c4 + 1] << 16);
    unsigned int hi = (unsigned int)tile[row][c4 + 2] | ((unsigned int)tile[row][c4 + 3] << 16);
    uint2 pk; pk.x = lo; pk.y = hi;
    int n = c0 + row;
    int ct = n >> 4, l15 = n & 15;
    int ks = t & 3;
    int quad = c4 >> 3;
    int j = c4 & 7;
    size_t off = (size_t)m * 16384 + (size_t)(((ct * 4 + ks) * 64) + quad * 16 + l15) * 8 + j;
    *(uint2*)&WT[off] = pk;
}

// ---------------- merged: ticket (blocks < tblocks, 1 edge/thread) + QKV MFMA ----------------
// Atomic latency of the ticket phase hides under co-resident MFMA blocks.
__global__ __launch_bounds__(256) void ticket_qkv_kernel(
    const int* __restrict__ dst, int* __restrict__ counts,
    int* __restrict__ ticket, int E, int tblocks,
    const float* __restrict__ h, const unsigned short* __restrict__ WT,
    const float* __restrict__ bq, const float* __restrict__ bk, const float* __restrict__ bv,
    unsigned short* __restrict__ Qb, unsigned char* __restrict__ K8,
    unsigned char* __restrict__ V8, int n) {
    __shared__ __align__(16) unsigned short wt[16384];   // 32 KB, frag-ordered
    int bx = blockIdx.x;
    int tid = threadIdx.x;
    if (bx < tblocks) {
        int e = bx * 256 + tid;
        if (e < E) ticket[e] = atomicAdd(&counts[dst[e]], 1);
        return;
    }
    int bid = bx - tblocks;
    int lane = tid & 63, wave = tid >> 6;
    int quad = lane >> 4, l15 = lane & 15;
    int rt = bid * 64 + wave * 16;

    // A-fragments: h rows rt+l15 (clamped; OOB rows never stored), fp32 -> bf16
    int rowA = min(rt + l15, n - 1);
    bf16x8 af[4];
#pragma unroll
    for (int ks = 0; ks < 4; ++ks) {
        const float* ap = &h[(size_t)rowA * D + ks * 32 + quad * 8];
        float4 a0 = *(const float4*)ap;
        float4 a1 = *(const float4*)(ap + 4);
        union { unsigned short u[8]; bf16x8 v; } pk;
        pk.u[0] = f2bf(a0.x); pk.u[1] = f2bf(a0.y);
        pk.u[2] = f2bf(a0.z); pk.u[3] = f2bf(a0.w);
        pk.u[4] = f2bf(a1.x); pk.u[5] = f2bf(a1.y);
        pk.u[6] = f2bf(a1.z); pk.u[7] = f2bf(a1.w);
        af[ks] = pk.v;
    }

    for (int m = 0; m < 3; ++m) {
        // linear 32 KB copy: lane-consecutive uint4, conflict-free both sides
#pragma unroll
        for (int it = 0; it < 8; ++it) {
            int idx = it * 256 + tid;
            *(uint4*)&wt[idx * 8] = *(const uint4*)&WT[(size_t)m * 16384 + idx * 8];
        }
        __syncthreads();

        f32x4 acc[8];
#pragma unroll
        for (int ct = 0; ct < 8; ++ct) {
            acc[ct] = (f32x4){0.f, 0.f, 0.f, 0.f};
#pragma unroll
            for (int ks = 0; ks < 4; ++ks) {
                bf16x8 bfr = *(const bf16x8*)&wt[((ct * 4 + ks) * 64 + lane) * 8];
                acc[ct] = __builtin_amdgcn_mfma_f32_16x16x32_bf16(af[ks], bfr, acc[ct], 0, 0, 0);
            }
        }
        __syncthreads();   // wt consumed before next m overwrites

        const float* bias = (m == 0) ? bq : (m == 1) ? bk : bv;
#pragma unroll
        for (int ct = 0; ct < 8; ++ct) {
            int col = ct * 16 + l15;
            float bb = bias[col];
#pragma unroll
            for (int r = 0; r < 4; ++r) {
                int row = rt + quad * 4 + r;
                if (row < n) {
                    float v = acc[ct][r] + bb;
                    if (m == 0)      Qb[(size_t)row * D + col] = f2bf(v);
                    else if (m == 1) K8[(size_t)row * D + col] = f2fp8(v);
                    else             V8[(size_t)row * D + col] = f2fp8(v);
                }
            }
        }
    }
}

// ---------------- parallel 3-phase scan ----------------
__device__ __forceinline__ int block_incl_scan256(int v, int tid, int* wsum) {
    int lane = tid & 63;
    int wid = tid >> 6;
#pragma unroll
    for (int off = 1; off < 64; off <<= 1) {
        int t = __shfl_up(v, off, 64);
        if (lane >= off) v += t;
    }
    if (lane == 63) wsum[wid] = v;
    __syncthreads();
#pragma unroll
    for (int w = 0; w < 4; ++w)
        if (w < wid) v += wsum[w];
    return v;
}

__global__ void scan1_kernel(const int* __restrict__ counts, int* __restrict__ offsets,
                             int* __restrict__ chunksum, int n) {
    __shared__ int wsum[4];
    int tid = threadIdx.x;
    int i = blockIdx.x * 256 + tid;
    int v = (i < n) ? counts[i] : 0;
    int incl = block_incl_scan256(v, tid, wsum);
    if (i < n) offsets[i + 1] = incl;
    if (tid == 255) chunksum[blockIdx.x] = incl;
}

__global__ void scan2_kernel(const int* __restrict__ chunksum, int* __restrict__ chunkbase, int nchunks) {
    __shared__ int wsum[4];
    int tid = threadIdx.x;
    int v = (tid < nchunks) ? chunksum[tid] : 0;
    int incl = block_incl_scan256(v, tid, wsum);
    if (tid < nchunks) chunkbase[tid] = incl - v;
}

__global__ void scan3_kernel(int* __restrict__ offsets, const int* __restrict__ chunkbase, int n) {
    int i = blockIdx.x * 256 + threadIdx.x;
    if (i < n) {
        offsets[i + 1] += chunkbase[blockIdx.x];
        if (i == 0) offsets[0] = 0;
    }
}

// ---------------- fill: pure scatter, no atomics ----------------
__global__ void fill_kernel(const int* __restrict__ dst, const int* __restrict__ src,
                            const int* __restrict__ ticket, const int* __restrict__ offsets,
                            int* __restrict__ psrc, int E) {
    int e = (blockIdx.x * 256 + threadIdx.x) * 4;
    if (e >= E) return;
    if (e + 3 < E) {
        int4 d4 = *(const int4*)&dst[e];
        int4 s4 = *(const int4*)&src[e];
        int4 t4 = *(const int4*)&ticket[e];
        psrc[offsets[d4.x] + t4.x] = s4.x;
        psrc[offsets[d4.y] + t4.y] = s4.y;
        psrc[offsets[d4.z] + t4.z] = s4.z;
        psrc[offsets[d4.w] + t4.w] = s4.w;
    } else {
        for (int i = e; i < E; ++i) psrc[offsets[dst[i]] + ticket[i]] = src[i];
    }
}

// ---------------- Edge attention (fp8 K/V), software-pipelined gathers ----------------
// One wave per dst node. lane = j*8 + hd: j = edge slot (0..7), hd = head (0..7, 16 dims).
__global__ __launch_bounds__(256) void edge_attn_kernel(
    const unsigned short* __restrict__ Qb, const unsigned char* __restrict__ K8,
    const unsigned char* __restrict__ V8,
    const int* __restrict__ offsets, const int* __restrict__ psrc,
    unsigned short* __restrict__ aggb, int n) {
    int wave = (blockIdx.x * 256 + threadIdx.x) >> 6;
    int lane = threadIdx.x & 63;
    if (wave >= n) return;
    int start = offsets[wave], end = offsets[wave + 1];
    int j = lane >> 3, hd = lane & 7;

    const unsigned short* qp = &Qb[(size_t)wave * D + hd * 16];
    uint4 qa = *(const uint4*)qp;
    uint4 qb = *(const uint4*)(qp + 8);
    float q[16];
    q[0] = bf2f_lo(qa.x);  q[1] = bf2f_hi(qa.x);
    q[2] = bf2f_lo(qa.y);  q[3] = bf2f_hi(qa.y);
    q[4] = bf2f_lo(qa.z);  q[5] = bf2f_hi(qa.z);
    q[6] = bf2f_lo(qa.w);  q[7] = bf2f_hi(qa.w);
    q[8] = bf2f_lo(qb.x);  q[9] = bf2f_hi(qb.x);
    q[10] = bf2f_lo(qb.y); q[11] = bf2f_hi(qb.y);
    q[12] = bf2f_lo(qb.z); q[13] = bf2f_hi(qb.z);
    q[14] = bf2f_lo(qb.w); q[15] = bf2f_hi(qb.w);

    float l = 0.f;
    float acc[16] = {};

    if (start < end) {
        int s = psrc[min(start + j, end - 1)];
        uint4 ku = *(const uint4*)&K8[(size_t)s * D + hd * 16];
        uint4 vu = *(const uint4*)&V8[(size_t)s * D + hd * 16];
        for (int base = start; base < end; base += 8) {
            int nb = base + 8;
            int sn = (nb < end) ? psrc[min(nb + j, end - 1)] : 0;
            // prefetch next iteration's K/V rows (dummy row 0 on last iteration)
            uint4 kun = *(const uint4*)&K8[(size_t)sn * D + hd * 16];
            uint4 vun = *(const uint4*)&V8[(size_t)sn * D + hd * 16];
            bool valid = (base + j) < end;

            float kf[16], vf[16];
            {
                f32x2 t;
                t = __builtin_amdgcn_cvt_pk_f32_fp8(ku.x, false); kf[0] = t.x;  kf[1] = t.y;
                t = __builtin_amdgcn_cvt_pk_f32_fp8(ku.x, true);  kf[2] = t.x;  kf[3] = t.y;
                t = __builtin_amdgcn_cvt_pk_f32_fp8(ku.y, false); kf[4] = t.x;  kf[5] = t.y;
                t = __builtin_amdgcn_cvt_pk_f32_fp8(ku.y, true);  kf[6] = t.x;  kf[7] = t.y;
                t = __builtin_amdgcn_cvt_pk_f32_fp8(ku.z, false); kf[8] = t.x;  kf[9] = t.y;
                t = __builtin_amdgcn_cvt_pk_f32_fp8(ku.z, true);  kf[10] = t.x; kf[11] = t.y;
                t = __builtin_amdgcn_cvt_pk_f32_fp8(ku.w, false); kf[12] = t.x; kf[13] = t.y;
                t = __builtin_amdgcn_cvt_pk_f32_fp8(ku.w, true);  kf[14] = t.x; kf[15] = t.y;
                t = __builtin_amdgcn_cvt_pk_f32_fp8(vu.x, false); vf[0] = t.x;  vf[1] = t.y;
                t = __builtin_amdgcn_cvt_pk_f32_fp8(vu.x, true);  vf[2] = t.x;  vf[3] = t.y;
                t = __builtin_amdgcn_cvt_pk_f32_fp8(vu.y, false); vf[4] = t.x;  vf[5] = t.y;
                t = __builtin_amdgcn_cvt_pk_f32_fp8(vu.y, true);  vf[6] = t.x;  vf[7] = t.y;
                t = __builtin_amdgcn_cvt_pk_f32_fp8(vu.z, false); vf[8] = t.x;  vf[9] = t.y;
                t = __builtin_amdgcn_cvt_pk_f32_fp8(vu.z, true);  vf[10] = t.x; vf[11] = t.y;
                t = __builtin_amdgcn_cvt_pk_f32_fp8(vu.w, false); vf[12] = t.x; vf[13] = t.y;
                t = __builtin_amdgcn_cvt_pk_f32_fp8(vu.w, true);  vf[14] = t.x; vf[15] = t.y;
            }

            float sc = q[0] * kf[0];
#pragma unroll
            for (int i = 1; i < 16; ++i) sc = fmaf(q[i], kf[i], sc);

            float p = valid ? __expf(sc) : 0.f;
            l += p;
#pragma unroll
            for (int i = 0; i < 16; ++i) acc[i] = fmaf(p, vf[i], acc[i]);
            ku = kun; vu = vun; s = sn;
        }
    }

    // combine the 8 edge slots (lanes differing in bits 3,4,5)
#pragma unroll
    for (int off = 8; off <= 32; off <<= 1) {
        l += __shfl_xor(l, off, 64);
#pragma unroll
        for (int i = 0; i < 16; ++i) acc[i] += __shfl_xor(acc[i], off, 64);
    }
    float inv = (l > 0.f) ? 1.f / l : 0.f;
    if (j == 0) {
        uint4 o0, o1;
        o0.x = (unsigned int)f2bf(acc[0] * inv) | ((unsigned int)f2bf(acc[1] * inv) << 16);
        o0.y = (unsigned int)f2bf(acc[2] * inv) | ((unsigned int)f2bf(acc[3] * inv) << 16);
        o0.z = (unsigned int)f2bf(acc[4] * inv) | ((unsigned int)f2bf(acc[5] * inv) << 16);
        o0.w = (unsigned int)f2bf(acc[6] * inv) | ((unsigned int)f2bf(acc[7] * inv) << 16);
        o1.x = (unsigned int)f2bf(acc[8] * inv) | ((unsigned int)f2bf(acc[9] * inv) << 16);
        o1.y = (unsigned int)f2bf(acc[10] * inv) | ((unsigned int)f2bf(acc[11] * inv) << 16);
        o1.z = (unsigned int)f2bf(acc[12] * inv) | ((unsigned int)f2bf(acc[13] * inv) << 16);
        o1.w = (unsigned int)f2bf(acc[14] * inv) | ((unsigned int)f2bf(acc[15] * inv) << 16);
        unsigned short* op = &aggb[(size_t)wave * D + hd * 16];
        *(uint4*)op = o0;
        *(uint4*)(op + 8) = o1;
    }
}

// ---------------- Output GEMM + bias + residual + LayerNorm (frag-ordered WTo, coalesced) ----------------
__global__ __launch_bounds__(256) void out_ln_mfma_kernel(
    const unsigned short* __restrict__ aggb, const unsigned short* __restrict__ WTo,
    const float* __restrict__ bo, const float* __restrict__ hres,
    const float* __restrict__ gamma, const float* __restrict__ beta,
    float* __restrict__ out, int n) {
    int tid = threadIdx.x;
    int lane = tid & 63, wave = tid >> 6;
    int quad = lane >> 4, l15 = lane & 15;
    int rt = blockIdx.x * 64 + wave * 16;

    int rowA = min(rt + l15, n - 1);
    bf16x8 af[4];
#pragma unroll
    for (int ks = 0; ks < 4; ++ks)
        af[ks] = *(const bf16x8*)&aggb[(size_t)rowA * D + ks * 32 + quad * 8];

    f32x4 acc[8];
#pragma unroll
    for (int ct = 0; ct < 8; ++ct) {
        acc[ct] = (f32x4){0.f, 0.f, 0.f, 0.f};
#pragma unroll
        for (int ks = 0; ks < 4; ++ks) {
            bf16x8 bfr = *(const bf16x8*)&WTo[(size_t)((ct * 4 + ks) * 64 + lane) * 8];
            acc[ct] = __builtin_amdgcn_mfma_f32_16x16x32_bf16(af[ks], bfr, acc[ct], 0, 0, 0);
        }
    }

    float bb[8], gg[8], be[8];
#pragma unroll
    for (int ct = 0; ct < 8; ++ct) {
        int col = ct * 16 + l15;
        bb[ct] = bo[col];
        gg[ct] = gamma[col];
        be[ct] = beta[col];
    }
#pragma unroll
    for (int ct = 0; ct < 8; ++ct) {
        int col = ct * 16 + l15;
#pragma unroll
        for (int r = 0; r < 4; ++r) {
            int row = rt + quad * 4 + r;
            float hv = (row < n) ? hres[(size_t)row * D + col] : 0.f;
            acc[ct][r] = acc[ct][r] + bb[ct] + hv;
        }
    }

#pragma unroll
    for (int r = 0; r < 4; ++r) {
        float s1 = 0.f, s2 = 0.f;
#pragma unroll
        for (int ct = 0; ct < 8; ++ct) {
            float v = acc[ct][r];
            s1 += v;
            s2 += v * v;
        }
        s1 += __shfl_xor(s1, 1, 64); s2 += __shfl_xor(s2, 1, 64);
        s1 += __shfl_xor(s1, 2, 64); s2 += __shfl_xor(s2, 2, 64);
        s1 += __shfl_xor(s1, 4, 64); s2 += __shfl_xor(s2, 4, 64);
        s1 += __shfl_xor(s1, 8, 64); s2 += __shfl_xor(s2, 8, 64);
        float mu = s1 * (1.f / 128.f);
        float var = s2 * (1.f / 128.f) - mu * mu;
        float rs = rsqrtf(fmaxf(var, 0.f) + EPS);
        int row = rt + quad * 4 + r;
        if (row < n) {
#pragma unroll
            for (int ct = 0; ct < 8; ++ct) {
                int col = ct * 16 + l15;
                out[(size_t)row * D + col] = (acc[ct][r] - mu) * rs * gg[ct] + be[ct];
            }
        }
    }
}

// ---------------- launch ----------------
extern "C" void kernel_launch(void* const* d_in, const int* in_sizes, int n_in,
                              void* d_out, int out_size, void* d_ws, size_t ws_size,
                              hipStream_t stream) {
    const float* h     = (const float*)d_in[0];
    const float* Wq    = (const float*)d_in[1];
    const float* bq    = (const float*)d_in[2];
    const float* Wk    = (const float*)d_in[3];
    const float* bk    = (const float*)d_in[4];
    const float* Wv    = (const float*)d_in[5];
    const float* bv    = (const float*)d_in[6];
    const float* Wo    = (const float*)d_in[7];
    const float* bo    = (const float*)d_in[8];
    const float* gamma = (const float*)d_in[9];
    const float* beta  = (const float*)d_in[10];
    const int* src     = (const int*)d_in[11];
    const int* dst     = (const int*)d_in[12];
    float* out = (float*)d_out;

    int N = in_sizes[0] / D;
    int E = in_sizes[11];

    // workspace layout
    unsigned short* Qb = (unsigned short*)d_ws;               // N*D bf16
    unsigned short* Ab = Qb + (size_t)N * D;                  // N*D bf16
    unsigned short* WT = Ab + (size_t)N * D;                  // 4*D*D bf16 (frag order)
    unsigned char* K8  = (unsigned char*)(WT + 4 * D * D);    // N*D fp8
    unsigned char* V8  = K8 + (size_t)N * D;                  // N*D fp8
    int* counts   = (int*)(V8 + (size_t)N * D);
    int* offsets  = counts + N;
    int* chunksum = offsets + (N + 1);
    int* chunkbase = chunksum + 256;
    int* ticket   = chunkbase + 256;
    int* psrc     = ticket + E;

    int nchunks = (N + 255) / 256;
    int e4blocks = ((E + 3) / 4 + 255) / 256;
    int tblocks = (E + 255) / 256;
    int nqkv = (N + 63) / 64;

    hipMemsetAsync(counts, 0, (size_t)N * sizeof(int), stream);
    wconv_kernel<<<64, 256, 0, stream>>>(Wq, Wk, Wv, Wo, WT);
    ticket_qkv_kernel<<<tblocks + nqkv, 256, 0, stream>>>(
        dst, counts, ticket, E, tblocks,
        h, WT, bq, bk, bv, Qb, K8, V8, N);
    scan1_kernel<<<nchunks, 256, 0, stream>>>(counts, offsets, chunksum, N);
    scan2_kernel<<<1, 256, 0, stream>>>(chunksum, chunkbase, nchunks);
    scan3_kernel<<<nchunks, 256, 0, stream>>>(offsets, chunkbase, N);
    fill_kernel<<<e4blocks, 256, 0, stream>>>(dst, src, ticket, offsets, psrc, E);
    edge_attn_kernel<<<(N + 3) / 4, 256, 0, stream>>>(Qb, K8, V8, offsets, psrc, Ab, N);
    out_ln_mfma_kernel<<<(N + 63) / 64, 256, 0, stream>>>(Ab, WT + 3 * D * D, bo, h, gamma, beta, out, N);
}

// Round 12
// 223.100 us; speedup vs baseline: 1.0202x; 1.0202x over previous
//
#include <hip/hip_runtime.h>
#include <hip/hip_bf16.h>
#include <math.h>

#define D 128
#define EPS 1e-12f
#define CPAD 16   // one counter per 64B cache line: kills same-line atomic serialization

typedef __attribute__((ext_vector_type(8))) short bf16x8;
typedef __attribute__((ext_vector_type(4))) float f32x4;
typedef __attribute__((ext_vector_type(2))) float f32x2;

// float -> bf16 round-to-nearest-even (finite inputs)
__device__ __forceinline__ unsigned short f2bf(float f) {
    unsigned int u = __float_as_uint(f);
    return (unsigned short)((u + 0x7fffu + ((u >> 16) & 1u)) >> 16);
}
__device__ __forceinline__ float bf2f_lo(unsigned int packed) {
    return __uint_as_float(packed << 16);
}
__device__ __forceinline__ float bf2f_hi(unsigned int packed) {
    return __uint_as_float(packed & 0xffff0000u);
}
__device__ __forceinline__ unsigned char f2fp8(float f) {
    return (unsigned char)__builtin_amdgcn_cvt_pk_fp8_f32(f, f, 0, false);
}

// ---------------- merged: W convert to MFMA-fragment order (blocks 0..63) + ticket ----------------
// Fragment order: WT[m*16384 + ((ct*4+ks)*64 + quad*16 + l15)*8 + j]
//   holds element (n = ct*16+l15, k = ks*32+quad*8+j) of W_m^T  (bf16)
__global__ __launch_bounds__(256) void prep_kernel(
    const float* __restrict__ Wq, const float* __restrict__ Wk,
    const float* __restrict__ Wv, const float* __restrict__ Wo,
    unsigned short* __restrict__ WT,
    const int* __restrict__ dst, int* __restrict__ counts,
    int* __restrict__ ticket, int E) {
    int bx = blockIdx.x;
    int tid = threadIdx.x;
    if (bx < 64) {
        __shared__ unsigned short tile[32][33];
        int m = bx >> 4;
        int t = bx & 15;
        const float* W = (m == 0) ? Wq : (m == 1) ? Wk : (m == 2) ? Wv : Wo;
        int r0 = (t & 3) * 32;   // k block
        int c0 = (t >> 2) * 32;  // n block
        int row = tid >> 3, c4 = (tid & 7) * 4;
        float4 v = *(const float4*)&W[(size_t)(r0 + row) * D + c0 + c4];
        tile[c4 + 0][row] = f2bf(v.x);
        tile[c4 + 1][row] = f2bf(v.y);
        tile[c4 + 2][row] = f2bf(v.z);
        tile[c4 + 3][row] = f2bf(v.w);
        __syncthreads();
        unsigned int lo = (unsigned int)tile[row][c4] | ((unsigned int)tile[row][c4 + 1] << 16);
        unsigned int hi = (unsigned int)tile[row][c4 + 2] | ((unsigned int)tile[row][c4 + 3] << 16);
        uint2 pk; pk.x = lo; pk.y = hi;
        int n = c0 + row;
        int ct = n >> 4, l15 = n & 15;
        int ks = t & 3;
        int quad = c4 >> 3;
        int j = c4 & 7;
        size_t off = (size_t)m * 16384 + (size_t)(((ct * 4 + ks) * 64) + quad * 16 + l15) * 8 + j;
        *(uint2*)&WT[off] = pk;
    } else {
        int e = ((bx - 64) * 256 + tid) * 4;
        if (e >= E) return;
        if (e + 3 < E) {
            int4 d4 = *(const int4*)&dst[e];
            int4 t4;
            t4.x = atomicAdd(&counts[d4.x * CPAD], 1);
            t4.y = atomicAdd(&counts[d4.y * CPAD], 1);
            t4.z = atomicAdd(&counts[d4.z * CPAD], 1);
            t4.w = atomicAdd(&counts[d4.w * CPAD], 1);
            *(int4*)&ticket[e] = t4;
        } else {
            for (int i = e; i < E; ++i) ticket[i] = atomicAdd(&counts[dst[i] * CPAD], 1);
        }
    }
}

// ---------------- parallel 3-phase scan ----------------
__device__ __forceinline__ int block_incl_scan256(int v, int tid, int* wsum) {
    int lane = tid & 63;
    int wid = tid >> 6;
#pragma unroll
    for (int off = 1; off < 64; off <<= 1) {
        int t = __shfl_up(v, off, 64);
        if (lane >= off) v += t;
    }
    if (lane == 63) wsum[wid] = v;
    __syncthreads();
#pragma unroll
    for (int w = 0; w < 4; ++w)
        if (w < wid) v += wsum[w];
    return v;
}

__global__ void scan1_kernel(const int* __restrict__ counts, int* __restrict__ offsets,
                             int* __restrict__ chunksum, int n) {
    __shared__ int wsum[4];
    int tid = threadIdx.x;
    int i = blockIdx.x * 256 + tid;
    int v = (i < n) ? counts[i * CPAD] : 0;
    int incl = block_incl_scan256(v, tid, wsum);
    if (i < n) offsets[i + 1] = incl;
    if (tid == 255) chunksum[blockIdx.x] = incl;
}

__global__ void scan2_kernel(const int* __restrict__ chunksum, int* __restrict__ chunkbase, int nchunks) {
    __shared__ int wsum[4];
    int tid = threadIdx.x;
    int v = (tid < nchunks) ? chunksum[tid] : 0;
    int incl = block_incl_scan256(v, tid, wsum);
    if (tid < nchunks) chunkbase[tid] = incl - v;
}

__global__ void scan3_kernel(int* __restrict__ offsets, const int* __restrict__ chunkbase, int n) {
    int i = blockIdx.x * 256 + threadIdx.x;
    if (i < n) {
        offsets[i + 1] += chunkbase[blockIdx.x];
        if (i == 0) offsets[0] = 0;
    }
}

// ---------------- merged: fill scatter (blocks < e4blocks) + QKV MFMA (rest) ----------------
__global__ __launch_bounds__(256) void fill_qkv_kernel(
    const int* __restrict__ dst, const int* __restrict__ src,
    const int* __restrict__ ticket, const int* __restrict__ offsets,
    int* __restrict__ psrc, int E, int e4blocks,
    const float* __restrict__ h, const unsigned short* __restrict__ WT,
    const float* __restrict__ bq, const float* __restrict__ bk, const float* __restrict__ bv,
    unsigned short* __restrict__ Qb, unsigned char* __restrict__ K8,
    unsigned char* __restrict__ V8, int n) {
    __shared__ __align__(16) unsigned short wt[16384];   // 32 KB, frag-ordered
    int bx = blockIdx.x;
    int tid = threadIdx.x;
    if (bx < e4blocks) {
        int e = (bx * 256 + tid) * 4;
        if (e >= E) return;
        if (e + 3 < E) {
            int4 d4 = *(const int4*)&dst[e];
            int4 s4 = *(const int4*)&src[e];
            int4 t4 = *(const int4*)&ticket[e];
            psrc[offsets[d4.x] + t4.x] = s4.x;
            psrc[offsets[d4.y] + t4.y] = s4.y;
            psrc[offsets[d4.z] + t4.z] = s4.z;
            psrc[offsets[d4.w] + t4.w] = s4.w;
        } else {
            for (int i = e; i < E; ++i) psrc[offsets[dst[i]] + ticket[i]] = src[i];
        }
        return;
    }
    int bid = bx - e4blocks;
    int lane = tid & 63, wave = tid >> 6;
    int quad = lane >> 4, l15 = lane & 15;
    int rt = bid * 64 + wave * 16;

    // A-fragments: h rows rt+l15 (clamped; OOB rows never stored), fp32 -> bf16
    int rowA = min(rt + l15, n - 1);
    bf16x8 af[4];
#pragma unroll
    for (int ks = 0; ks < 4; ++ks) {
        const float* ap = &h[(size_t)rowA * D + ks * 32 + quad * 8];
        float4 a0 = *(const float4*)ap;
        float4 a1 = *(const float4*)(ap + 4);
        union { unsigned short u[8]; bf16x8 v; } pk;
        pk.u[0] = f2bf(a0.x); pk.u[1] = f2bf(a0.y);
        pk.u[2] = f2bf(a0.z); pk.u[3] = f2bf(a0.w);
        pk.u[4] = f2bf(a1.x); pk.u[5] = f2bf(a1.y);
        pk.u[6] = f2bf(a1.z); pk.u[7] = f2bf(a1.w);
        af[ks] = pk.v;
    }

    for (int m = 0; m < 3; ++m) {
        // linear 32 KB copy: lane-consecutive uint4, conflict-free both sides
#pragma unroll
        for (int it = 0; it < 8; ++it) {
            int idx = it * 256 + tid;
            *(uint4*)&wt[idx * 8] = *(const uint4*)&WT[(size_t)m * 16384 + idx * 8];
        }
        __syncthreads();

        f32x4 acc[8];
#pragma unroll
        for (int ct = 0; ct < 8; ++ct) {
            acc[ct] = (f32x4){0.f, 0.f, 0.f, 0.f};
#pragma unroll
            for (int ks = 0; ks < 4; ++ks) {
                bf16x8 bfr = *(const bf16x8*)&wt[((ct * 4 + ks) * 64 + lane) * 8];
                acc[ct] = __builtin_amdgcn_mfma_f32_16x16x32_bf16(af[ks], bfr, acc[ct], 0, 0, 0);
            }
        }
        __syncthreads();   // wt consumed before next m overwrites

        const float* bias = (m == 0) ? bq : (m == 1) ? bk : bv;
#pragma unroll
        for (int ct = 0; ct < 8; ++ct) {
            int col = ct * 16 + l15;
            float bb = bias[col];
#pragma unroll
            for (int r = 0; r < 4; ++r) {
                int row = rt + quad * 4 + r;
                if (row < n) {
                    float v = acc[ct][r] + bb;
                    if (m == 0)      Qb[(size_t)row * D + col] = f2bf(v);
                    else if (m == 1) K8[(size_t)row * D + col] = f2fp8(v);
                    else             V8[(size_t)row * D + col] = f2fp8(v);
                }
            }
        }
    }
}

// ---------------- Edge attention (fp8 K/V) ----------------
// One wave per dst node. lane = j*8 + hd: j = edge slot (0..7), hd = head (0..7, 16 dims).
__global__ __launch_bounds__(256) void edge_attn_kernel(
    const unsigned short* __restrict__ Qb, const unsigned char* __restrict__ K8,
    const unsigned char* __restrict__ V8,
    const int* __restrict__ offsets, const int* __restrict__ psrc,
    unsigned short* __restrict__ aggb, int n) {
    int wave = (blockIdx.x * 256 + threadIdx.x) >> 6;
    int lane = threadIdx.x & 63;
    if (wave >= n) return;
    int start = offsets[wave], end = offsets[wave + 1];
    int j = lane >> 3, hd = lane & 7;

    const unsigned short* qp = &Qb[(size_t)wave * D + hd * 16];
    uint4 qa = *(const uint4*)qp;
    uint4 qb = *(const uint4*)(qp + 8);
    float q[16];
    q[0] = bf2f_lo(qa.x);  q[1] = bf2f_hi(qa.x);
    q[2] = bf2f_lo(qa.y);  q[3] = bf2f_hi(qa.y);
    q[4] = bf2f_lo(qa.z);  q[5] = bf2f_hi(qa.z);
    q[6] = bf2f_lo(qa.w);  q[7] = bf2f_hi(qa.w);
    q[8] = bf2f_lo(qb.x);  q[9] = bf2f_hi(qb.x);
    q[10] = bf2f_lo(qb.y); q[11] = bf2f_hi(qb.y);
    q[12] = bf2f_lo(qb.z); q[13] = bf2f_hi(qb.z);
    q[14] = bf2f_lo(qb.w); q[15] = bf2f_hi(qb.w);

    float l = 0.f;
    float acc[16] = {};

    if (start < end) {
        int s = psrc[min(start + j, end - 1)];
        for (int base = start; base < end; base += 8) {
            uint4 ku = *(const uint4*)&K8[(size_t)s * D + hd * 16];
            uint4 vu = *(const uint4*)&V8[(size_t)s * D + hd * 16];
            int nb = base + 8;
            int sn = (nb < end) ? psrc[min(nb + j, end - 1)] : 0;
            bool valid = (base + j) < end;

            float kf[16], vf[16];
            {
                f32x2 t;
                t = __builtin_amdgcn_cvt_pk_f32_fp8(ku.x, false); kf[0] = t.x;  kf[1] = t.y;
                t = __builtin_amdgcn_cvt_pk_f32_fp8(ku.x, true);  kf[2] = t.x;  kf[3] = t.y;
                t = __builtin_amdgcn_cvt_pk_f32_fp8(ku.y, false); kf[4] = t.x;  kf[5] = t.y;
                t = __builtin_amdgcn_cvt_pk_f32_fp8(ku.y, true);  kf[6] = t.x;  kf[7] = t.y;
                t = __builtin_amdgcn_cvt_pk_f32_fp8(ku.z, false); kf[8] = t.x;  kf[9] = t.y;
                t = __builtin_amdgcn_cvt_pk_f32_fp8(ku.z, true);  kf[10] = t.x; kf[11] = t.y;
                t = __builtin_amdgcn_cvt_pk_f32_fp8(ku.w, false); kf[12] = t.x; kf[13] = t.y;
                t = __builtin_amdgcn_cvt_pk_f32_fp8(ku.w, true);  kf[14] = t.x; kf[15] = t.y;
                t = __builtin_amdgcn_cvt_pk_f32_fp8(vu.x, false); vf[0] = t.x;  vf[1] = t.y;
                t = __builtin_amdgcn_cvt_pk_f32_fp8(vu.x, true);  vf[2] = t.x;  vf[3] = t.y;
                t = __builtin_amdgcn_cvt_pk_f32_fp8(vu.y, false); vf[4] = t.x;  vf[5] = t.y;
                t = __builtin_amdgcn_cvt_pk_f32_fp8(vu.y, true);  vf[6] = t.x;  vf[7] = t.y;
                t = __builtin_amdgcn_cvt_pk_f32_fp8(vu.z, false); vf[8] = t.x;  vf[9] = t.y;
                t = __builtin_amdgcn_cvt_pk_f32_fp8(vu.z, true);  vf[10] = t.x; vf[11] = t.y;
                t = __builtin_amdgcn_cvt_pk_f32_fp8(vu.w, false); vf[12] = t.x; vf[13] = t.y;
                t = __builtin_amdgcn_cvt_pk_f32_fp8(vu.w, true);  vf[14] = t.x; vf[15] = t.y;
            }

            float sc = q[0] * kf[0];
#pragma unroll
            for (int i = 1; i < 16; ++i) sc = fmaf(q[i], kf[i], sc);

            float p = valid ? __expf(sc) : 0.f;
            l += p;
#pragma unroll
            for (int i = 0; i < 16; ++i) acc[i] = fmaf(p, vf[i], acc[i]);
            s = sn;
        }
    }

    // combine the 8 edge slots (lanes differing in bits 3,4,5)
#pragma unroll
    for (int off = 8; off <= 32; off <<= 1) {
        l += __shfl_xor(l, off, 64);
#pragma unroll
        for (int i = 0; i < 16; ++i) acc[i] += __shfl_xor(acc[i], off, 64);
    }
    float inv = (l > 0.f) ? 1.f / l : 0.f;
    if (j == 0) {
        uint4 o0, o1;
        o0.x = (unsigned int)f2bf(acc[0] * inv) | ((unsigned int)f2bf(acc[1] * inv) << 16);
        o0.y = (unsigned int)f2bf(acc[2] * inv) | ((unsigned int)f2bf(acc[3] * inv) << 16);
        o0.z = (unsigned int)f2bf(acc[4] * inv) | ((unsigned int)f2bf(acc[5] * inv) << 16);
        o0.w = (unsigned int)f2bf(acc[6] * inv) | ((unsigned int)f2bf(acc[7] * inv) << 16);
        o1.x = (unsigned int)f2bf(acc[8] * inv) | ((unsigned int)f2bf(acc[9] * inv) << 16);
        o1.y = (unsigned int)f2bf(acc[10] * inv) | ((unsigned int)f2bf(acc[11] * inv) << 16);
        o1.z = (unsigned int)f2bf(acc[12] * inv) | ((unsigned int)f2bf(acc[13] * inv) << 16);
        o1.w = (unsigned int)f2bf(acc[14] * inv) | ((unsigned int)f2bf(acc[15] * inv) << 16);
        unsigned short* op = &aggb[(size_t)wave * D + hd * 16];
        *(uint4*)op = o0;
        *(uint4*)(op + 8) = o1;
    }
}

// ---------------- Output GEMM + bias + residual + LayerNorm (frag-ordered WTo, coalesced) ----------------
__global__ __launch_bounds__(256) void out_ln_mfma_kernel(
    const unsigned short* __restrict__ aggb, const unsigned short* __restrict__ WTo,
    const float* __restrict__ bo, const float* __restrict__ hres,
    const float* __restrict__ gamma, const float* __restrict__ beta,
    float* __restrict__ out, int n) {
    int tid = threadIdx.x;
    int lane = tid & 63, wave = tid >> 6;
    int quad = lane >> 4, l15 = lane & 15;
    int rt = blockIdx.x * 64 + wave * 16;

    int rowA = min(rt + l15, n - 1);
    bf16x8 af[4];
#pragma unroll
    for (int ks = 0; ks < 4; ++ks)
        af[ks] = *(const bf16x8*)&aggb[(size_t)rowA * D + ks * 32 + quad * 8];

    f32x4 acc[8];
#pragma unroll
    for (int ct = 0; ct < 8; ++ct) {
        acc[ct] = (f32x4){0.f, 0.f, 0.f, 0.f};
#pragma unroll
        for (int ks = 0; ks < 4; ++ks) {
            bf16x8 bfr = *(const bf16x8*)&WTo[(size_t)((ct * 4 + ks) * 64 + lane) * 8];
            acc[ct] = __builtin_amdgcn_mfma_f32_16x16x32_bf16(af[ks], bfr, acc[ct], 0, 0, 0);
        }
    }

    float bb[8], gg[8], be[8];
#pragma unroll
    for (int ct = 0; ct < 8; ++ct) {
        int col = ct * 16 + l15;
        bb[ct] = bo[col];
        gg[ct] = gamma[col];
        be[ct] = beta[col];
    }
#pragma unroll
    for (int ct = 0; ct < 8; ++ct) {
        int col = ct * 16 + l15;
#pragma unroll
        for (int r = 0; r < 4; ++r) {
            int row = rt + quad * 4 + r;
            float hv = (row < n) ? hres[(size_t)row * D + col] : 0.f;
            acc[ct][r] = acc[ct][r] + bb[ct] + hv;
        }
    }

#pragma unroll
    for (int r = 0; r < 4; ++r) {
        float s1 = 0.f, s2 = 0.f;
#pragma unroll
        for (int ct = 0; ct < 8; ++ct) {
            float v = acc[ct][r];
            s1 += v;
            s2 += v * v;
        }
        s1 += __shfl_xor(s1, 1, 64); s2 += __shfl_xor(s2, 1, 64);
        s1 += __shfl_xor(s1, 2, 64); s2 += __shfl_xor(s2, 2, 64);
        s1 += __shfl_xor(s1, 4, 64); s2 += __shfl_xor(s2, 4, 64);
        s1 += __shfl_xor(s1, 8, 64); s2 += __shfl_xor(s2, 8, 64);
        float mu = s1 * (1.f / 128.f);
        float var = s2 * (1.f / 128.f) - mu * mu;
        float rs = rsqrtf(fmaxf(var, 0.f) + EPS);
        int row = rt + quad * 4 + r;
        if (row < n) {
#pragma unroll
            for (int ct = 0; ct < 8; ++ct) {
                int col = ct * 16 + l15;
                out[(size_t)row * D + col] = (acc[ct][r] - mu) * rs * gg[ct] + be[ct];
            }
        }
    }
}

// ---------------- launch ----------------
extern "C" void kernel_launch(void* const* d_in, const int* in_sizes, int n_in,
                              void* d_out, int out_size, void* d_ws, size_t ws_size,
                              hipStream_t stream) {
    const float* h     = (const float*)d_in[0];
    const float* Wq    = (const float*)d_in[1];
    const float* bq    = (const float*)d_in[2];
    const float* Wk    = (const float*)d_in[3];
    const float* bk    = (const float*)d_in[4];
    const float* Wv    = (const float*)d_in[5];
    const float* bv    = (const float*)d_in[6];
    const float* Wo    = (const float*)d_in[7];
    const float* bo    = (const float*)d_in[8];
    const float* gamma = (const float*)d_in[9];
    const float* beta  = (const float*)d_in[10];
    const int* src     = (const int*)d_in[11];
    const int* dst     = (const int*)d_in[12];
    float* out = (float*)d_out;

    int N = in_sizes[0] / D;
    int E = in_sizes[11];

    // workspace layout
    unsigned short* Qb = (unsigned short*)d_ws;               // N*D bf16
    unsigned short* Ab = Qb + (size_t)N * D;                  // N*D bf16
    unsigned short* WT = Ab + (size_t)N * D;                  // 4*D*D bf16 (frag order)
    unsigned char* K8  = (unsigned char*)(WT + 4 * D * D);    // N*D fp8
    unsigned char* V8  = K8 + (size_t)N * D;                  // N*D fp8
    int* counts   = (int*)(V8 + (size_t)N * D);               // N*CPAD (padded, 1/line)
    int* offsets  = counts + (size_t)N * CPAD;
    int* chunksum = offsets + (N + 1);
    int* chunkbase = chunksum + 256;
    int* ticket   = chunkbase + 256;
    int* psrc     = ticket + E;

    int nchunks = (N + 255) / 256;
    int e4blocks = ((E + 3) / 4 + 255) / 256;
    int nqkv = (N + 63) / 64;

    hipMemsetAsync(counts, 0, (size_t)N * CPAD * sizeof(int), stream);
    prep_kernel<<<64 + e4blocks, 256, 0, stream>>>(Wq, Wk, Wv, Wo, WT, dst, counts, ticket, E);
    scan1_kernel<<<nchunks, 256, 0, stream>>>(counts, offsets, chunksum, N);
    scan2_kernel<<<1, 256, 0, stream>>>(chunksum, chunkbase, nchunks);
    scan3_kernel<<<nchunks, 256, 0, stream>>>(offsets, chunkbase, N);
    fill_qkv_kernel<<<e4blocks + nqkv, 256, 0, stream>>>(
        dst, src, ticket, offsets, psrc, E, e4blocks,
        h, WT, bq, bk, bv, Qb, K8, V8, N);
    edge_attn_kernel<<<(N + 3) / 4, 256, 0, stream>>>(Qb, K8, V8, offsets, psrc, Ab, N);
    out_ln_mfma_kernel<<<(N + 63) / 64, 256, 0, stream>>>(Ab, WT + 3 * D * D, bo, h, gamma, beta, out, N);
}